// Round 1
// 6304.211 us; speedup vs baseline: 2.8929x; 2.8929x over previous
//
#include <hip/hip_runtime.h>
#include <hip/hip_bf16.h>
#include <cstddef>

// LSTM B=64,S=512,D=H=1024. Round 3 structure:
//  prep: bar init + x->bf16 ; transpose W,U -> [4096][1024] bf16 (W16T/U16T)
//  gemm_xw: xW = x@W precomputed to ws (fp32 if ws allows, else bf16, else in-loop)
//  lstm_rec: 256 WGs x 256 thr. 4 batch-blocks of 16 batches (independent!),
//   64 WGs/block each owning 16 h-cols. U-slice in REGISTERS (32 x short8/lane).
//   h exchanged via 32KB LDS stage. Per-block tree barrier (4 leaves x 16 + root).
//  R3 change: FENCE-FREE exchange protocol. All cross-WG traffic (h tiles,
//   barrier words) uses device-scope cache-bypassing accesses (sc1 write-through
//   stores, RELAXED-AGENT atomic loads) + explicit s_waitcnt vmcnt ordering.
//   No __builtin_amdgcn_fence => no buffer_wbl2 / buffer_inv in the loop
//   (previously ~32 cache-maintenance ops per XCD per step = ~30us/step stall).

typedef __attribute__((ext_vector_type(8))) short short8;
typedef __attribute__((ext_vector_type(4))) float f32x4;

static constexpr int Bc = 64, Sc = 512, Dc = 1024, Hc = 1024, G4c = 4096;

__device__ __forceinline__ unsigned short f2bf(float f) {
    unsigned int u = __float_as_uint(f);
    u = u + 0x7FFFu + ((u >> 16) & 1u);   // RNE
    return (unsigned short)(u >> 16);
}
__device__ __forceinline__ short f2bfs(float f) { return (short)f2bf(f); }
__device__ __forceinline__ float bf2f(unsigned short u) { return __uint_as_float(((unsigned int)u) << 16); }
__device__ __forceinline__ float sigmoidf_(float x) { return 1.0f / (1.0f + __expf(-x)); }
__device__ __forceinline__ float tanhf_(float x) { return 1.0f - 2.0f / (__expf(2.0f * x) + 1.0f); }

// ---------------- prep: barrier init + x fp32 -> bf16 ----------------
__global__ void __launch_bounds__(256) prep_misc(const float* __restrict__ x,
                                                 unsigned short* __restrict__ x16,
                                                 unsigned int* __restrict__ bar,
                                                 int n4, int use_x16) {
    if (blockIdx.x == 0) {
        for (int i = threadIdx.x; i < 1024; i += 256) bar[i] = 0u;
    }
    if (!use_x16) return;
    int i = blockIdx.x * 256 + threadIdx.x;
    const int stride = gridDim.x * 256;
    for (; i < n4; i += stride) {
        const float4 v = ((const float4*)x)[i];
        ushort4 o;
        o.x = f2bf(v.x); o.y = f2bf(v.y); o.z = f2bf(v.z); o.w = f2bf(v.w);
        ((ushort4*)x16)[i] = o;
    }
}

// ---------------- transpose [1024][4096] fp32 -> [4096][1024] bf16 ----------------
__global__ void __launch_bounds__(256) transpose_bf16(const float* __restrict__ src,
                                                      unsigned short* __restrict__ dst) {
    __shared__ unsigned short T[64][72];
    const int kt = blockIdx.x >> 6;   // 0..15
    const int gt = blockIdx.x & 63;   // 0..63
    const int tr = threadIdx.x >> 6;  // 0..3
    const int tc = threadIdx.x & 63;  // 0..63
#pragma unroll
    for (int i = 0; i < 16; ++i) {
        const int r = i * 4 + tr;
        T[tc][r] = f2bf(src[(size_t)(kt * 64 + r) * G4c + gt * 64 + tc]);
    }
    __syncthreads();
#pragma unroll
    for (int i = 0; i < 16; ++i) {
        const int g = i * 4 + tr;
        dst[(size_t)(gt * 64 + g) * 1024 + kt * 64 + tc] = T[g][tc];
    }
}

// ---------------- xW GEMM: M=32768 (b,s), N=4096, K=1024; out layout [s][b][4096] ----------------
__global__ void __launch_bounds__(256) gemm_xw(const unsigned short* __restrict__ x16,
                                               const unsigned short* __restrict__ w16t,
                                               void* __restrict__ xw, int mode) {
    const int nt = blockIdx.x & 63;
    const int mt = blockIdx.x >> 6;        // 0..511
    const int w = threadIdx.x >> 6;
    const int lane = threadIdx.x & 63;
    const int q = lane >> 4, l16 = lane & 15;

    const unsigned short* abase = x16 + (size_t)(mt * 64 + w * 16 + l16) * 1024 + q * 8;
    const unsigned short* bbase = w16t + (size_t)(nt * 64 + l16) * 1024 + q * 8;

    f32x4 acc[4] = {{0,0,0,0},{0,0,0,0},{0,0,0,0},{0,0,0,0}};
#pragma unroll 8
    for (int kk = 0; kk < 32; ++kk) {
        short8 a = *(const short8*)(abase + kk * 32);
#pragma unroll
        for (int j = 0; j < 4; ++j) {
            short8 b = *(const short8*)(bbase + (size_t)j * 16 * 1024 + kk * 32);
            acc[j] = __builtin_amdgcn_mfma_f32_16x16x32_bf16(a, b, acc[j], 0, 0, 0);
        }
    }
    const int m0 = mt * 64 + w * 16 + q * 4;
#pragma unroll
    for (int j = 0; j < 4; ++j)
#pragma unroll
        for (int r = 0; r < 4; ++r) {
            const int m = m0 + r;
            const int b = m >> 9, s = m & 511;
            const size_t o = ((size_t)s * 64 + b) * G4c + nt * 64 + j * 16 + l16;
            if (mode == 2) ((float*)xw)[o] = acc[j][r];
            else ((unsigned short*)xw)[o] = f2bf(acc[j][r]);
        }
}

// ---------------- fence-free per-block barrier: 64 WGs = 4 leaves x 16 -> root of 4 ----------------
// Preconditions: all cross-WG data written with device-scope (sc1) write-through
// stores. Each wave drains its own stores (vmcnt(0)) before rendezvous; the
// releaser orders counter-resets before the flag store with an explicit vmcnt(0).
// All atomics RELAXED => no compiler-inserted buffer_wbl2/buffer_inv.
__device__ __forceinline__ void blk_barrier_nf(unsigned int* base, int cs, unsigned int gen) {
    asm volatile("s_waitcnt vmcnt(0)" ::: "memory");   // own h/out stores globally visible
    __syncthreads();
    if (threadIdx.x == 0) {
        unsigned int a = __hip_atomic_fetch_add(&base[16 + 8 * (cs >> 4)], 1u, __ATOMIC_RELAXED, __HIP_MEMORY_SCOPE_AGENT);
        bool rel = false;
        if (a == 15u) {
            unsigned int r = __hip_atomic_fetch_add(&base[8], 1u, __ATOMIC_RELAXED, __HIP_MEMORY_SCOPE_AGENT);
            if (r == 3u) {
                __hip_atomic_store(&base[8], 0u, __ATOMIC_RELAXED, __HIP_MEMORY_SCOPE_AGENT);
#pragma unroll
                for (int g = 0; g < 4; ++g)
                    __hip_atomic_store(&base[16 + 8 * g], 0u, __ATOMIC_RELAXED, __HIP_MEMORY_SCOPE_AGENT);
                asm volatile("s_waitcnt vmcnt(0)" ::: "memory");   // resets complete before flag issues
                __hip_atomic_store(&base[0], gen, __ATOMIC_RELAXED, __HIP_MEMORY_SCOPE_AGENT);
                rel = true;
            }
        }
        if (!rel) {
            while (__hip_atomic_load(&base[0], __ATOMIC_RELAXED, __HIP_MEMORY_SCOPE_AGENT) < gen)
                __builtin_amdgcn_s_sleep(2);
        }
    }
    __syncthreads();   // also the compiler/hw barrier keeping the sc1 h-loads after the flag
}

// ---------------- recurrence ----------------
__global__ void __launch_bounds__(256, 1) lstm_rec(
    const unsigned short* __restrict__ x16, const float* __restrict__ x,
    const unsigned short* __restrict__ w16t, const unsigned short* __restrict__ u16t,
    const float* __restrict__ bias, const void* __restrict__ xw,
    unsigned short* __restrict__ hbuf, unsigned int* __restrict__ bar,
    float* __restrict__ out, int xw_mode, int use_x16) {
    __shared__ short8 hsF[2048];   // 32 KB: A-frags of h, [kk][lane]
    __shared__ short8 xsF[2048];   // 32 KB: A-frags of x_t (mode 0 only)
    __shared__ float gbuf[4][16][17];

    const int tid = threadIdx.x;
    const int blk = blockIdx.x >> 6;      // batch block 0..3
    const int cs = blockIdx.x & 63;       // col slice 0..63
    const int col0 = cs * 16;
    const int wv = tid >> 6;
    const int lane = tid & 63;
    const int q = lane >> 4, l16 = lane & 15;
    const int bb = tid >> 4, cc = tid & 15;   // elementwise (batch, col)
    const int gcol = col0 + cc;
    unsigned int* bbar = bar + blk * 64;

    // bias registers
    const float bi = bias[gcol], bfv = bias[1024 + gcol], bg = bias[2048 + gcol], bo = bias[3072 + gcol];

    // U slice -> registers: 32 x short8 = 128 VGPRs
    short8 uf[32];
    {
        const unsigned short* ub = u16t + ((size_t)wv * 1024 + col0 + l16) * 1024 + q * 8;
#pragma unroll
        for (int kk = 0; kk < 32; ++kk) uf[kk] = *(const short8*)(ub + kk * 32);
    }
    // zero h frags (h_{-1} = 0)
    {
        const short8 z = {0, 0, 0, 0, 0, 0, 0, 0};
#pragma unroll
        for (int i = 0; i < 8; ++i) hsF[i * 256 + tid] = z;
    }
    // mode 0: stage x frags for t=0
    if (xw_mode == 0) {
#pragma unroll
        for (int i = 0; i < 8; ++i) {
            const int f = i * 256 + tid;
            const int kk = f >> 6, qq = (f >> 4) & 3, b2 = f & 15;
            if (use_x16) {
                const unsigned short* xs = x16 + ((size_t)(blk * 16 + b2) * Sc + 0) * Dc + kk * 32 + qq * 8;
                xsF[f] = *(const short8*)xs;
            } else {
                const float* xs = x + ((size_t)(blk * 16 + b2) * Sc + 0) * Dc + kk * 32 + qq * 8;
                float4 v0 = *(const float4*)xs, v1 = *(const float4*)(xs + 4);
                short8 s;
                s[0] = f2bfs(v0.x); s[1] = f2bfs(v0.y); s[2] = f2bfs(v0.z); s[3] = f2bfs(v0.w);
                s[4] = f2bfs(v1.x); s[5] = f2bfs(v1.y); s[6] = f2bfs(v1.z); s[7] = f2bfs(v1.w);
                xsF[f] = s;
            }
        }
    }
    // prefetch xW(t=0)
    float pxi = 0.f, pxf = 0.f, pxg = 0.f, pxo = 0.f;
    if (xw_mode == 1) {
        const unsigned short* p = (const unsigned short*)xw + ((size_t)0 * 64 + blk * 16 + bb) * G4c + gcol;
        pxi = bf2f(p[0]); pxf = bf2f(p[1024]); pxg = bf2f(p[2048]); pxo = bf2f(p[3072]);
    } else if (xw_mode == 2) {
        const float* p = (const float*)xw + ((size_t)0 * 64 + blk * 16 + bb) * G4c + gcol;
        pxi = p[0]; pxf = p[1024]; pxg = p[2048]; pxo = p[3072];
    }

    // per-thread base for the h-stage reads (frag f = i*256+tid; +256B per i)
    const int kk0 = tid >> 6, qq0 = (tid >> 4) & 3, b20 = tid & 15;

    float c = 0.f;
    for (int t = 0; t < Sc; ++t) {
        __syncthreads();   // staging (or init) visible
        f32x4 a0 = {0, 0, 0, 0}, a1 = {0, 0, 0, 0};
#pragma unroll
        for (int kk = 0; kk < 32; kk += 2) {
            a0 = __builtin_amdgcn_mfma_f32_16x16x32_bf16(hsF[kk * 64 + lane], uf[kk], a0, 0, 0, 0);
            a1 = __builtin_amdgcn_mfma_f32_16x16x32_bf16(hsF[(kk + 1) * 64 + lane], uf[kk + 1], a1, 0, 0, 0);
        }
        if (xw_mode == 0) {
            const unsigned short* wb = w16t + ((size_t)wv * 1024 + col0 + l16) * 1024 + q * 8;
#pragma unroll
            for (int kk = 0; kk < 32; kk += 2) {
                short8 w0 = *(const short8*)(wb + kk * 32);
                a0 = __builtin_amdgcn_mfma_f32_16x16x32_bf16(xsF[kk * 64 + lane], w0, a0, 0, 0, 0);
                short8 w1 = *(const short8*)(wb + (kk + 1) * 32);
                a1 = __builtin_amdgcn_mfma_f32_16x16x32_bf16(xsF[(kk + 1) * 64 + lane], w1, a1, 0, 0, 0);
            }
        }
#pragma unroll
        for (int r = 0; r < 4; ++r) gbuf[wv][q * 4 + r][l16] = a0[r] + a1[r];
        __syncthreads();
        // elementwise: thread (bb, cc)
        float gi = gbuf[0][bb][cc] + pxi + bi;
        float gf = gbuf[1][bb][cc] + pxf + bfv;
        float gg = gbuf[2][bb][cc] + pxg + bg;
        float go = gbuf[3][bb][cc] + pxo + bo;
        gi = sigmoidf_(gi); gf = sigmoidf_(gf); gg = tanhf_(gg); go = sigmoidf_(go);
        c = gf * c + gi * gg;
        const float h = go * tanhf_(c);
        // h store: device-scope write-through (sc1) => visible at coherent point
        // once vmcnt retires; no L2 writeback needed.
        {
            const unsigned short h16 = f2bf(h);
            unsigned short* hp = hbuf + (t & 1) * (Bc * Hc) + (blk * 16 + bb) * Hc + gcol;
            asm volatile("global_store_short %0, %1, off sc1" :: "v"(hp), "v"(h16) : "memory");
        }
        out[((size_t)(blk * 16 + bb) * Sc + t) * Hc + gcol] = h;
        if (t == Sc - 1) {
            out[(size_t)Bc * Sc * Hc + (size_t)(blk * 16 + bb) * Hc + gcol] = h;
            out[(size_t)Bc * Sc * Hc + (size_t)Bc * Hc + (size_t)(blk * 16 + bb) * Hc + gcol] = c;
        }
        if (t < Sc - 1) {
            blk_barrier_nf(bbar, cs, (unsigned int)(t + 1));
            // prefetch xW(t+1): ordinary cached loads; consumed after staging +
            // MFMA (~1-2us of slack), so HBM latency is hidden.
            if (xw_mode == 1) {
                const unsigned short* p = (const unsigned short*)xw + ((size_t)(t + 1) * 64 + blk * 16 + bb) * G4c + gcol;
                pxi = bf2f(p[0]); pxf = bf2f(p[1024]); pxg = bf2f(p[2048]); pxo = bf2f(p[3072]);
            } else if (xw_mode == 2) {
                const float* p = (const float*)xw + ((size_t)(t + 1) * 64 + blk * 16 + bb) * G4c + gcol;
                pxi = p[0]; pxf = p[1024]; pxg = p[2048]; pxo = p[3072];
            }
            // stage h_t frags: cache-bypassing device-scope loads (sc1) read the
            // coherent point directly -- no buffer_inv required.
            {
                const unsigned long long* ps = (const unsigned long long*)
                    (hbuf + (t & 1) * (Bc * Hc) + (size_t)(blk * 16 + b20) * Hc + kk0 * 32 + qq0 * 8);
                unsigned long long hv[16];
#pragma unroll
                for (int i = 0; i < 8; ++i) {
                    hv[2 * i]     = __hip_atomic_load(ps + i * 32,     __ATOMIC_RELAXED, __HIP_MEMORY_SCOPE_AGENT);
                    hv[2 * i + 1] = __hip_atomic_load(ps + i * 32 + 1, __ATOMIC_RELAXED, __HIP_MEMORY_SCOPE_AGENT);
                }
#pragma unroll
                for (int i = 0; i < 8; ++i) {
                    short8 s;
                    ((unsigned long long*)&s)[0] = hv[2 * i];
                    ((unsigned long long*)&s)[1] = hv[2 * i + 1];
                    hsF[i * 256 + tid] = s;
                }
            }
            // stage x_{t+1} frags (mode 0) -- read-only input, ordinary cached loads
            if (xw_mode == 0) {
#pragma unroll
                for (int i = 0; i < 8; ++i) {
                    const int f = i * 256 + tid;
                    const int kk = f >> 6, qq = (f >> 4) & 3, b2 = f & 15;
                    if (use_x16) {
                        const unsigned short* xs = x16 + ((size_t)(blk * 16 + b2) * Sc + (t + 1)) * Dc + kk * 32 + qq * 8;
                        xsF[f] = *(const short8*)xs;
                    } else {
                        const float* xs = x + ((size_t)(blk * 16 + b2) * Sc + (t + 1)) * Dc + kk * 32 + qq * 8;
                        float4 v0 = *(const float4*)xs, v1 = *(const float4*)(xs + 4);
                        short8 s;
                        s[0] = f2bfs(v0.x); s[1] = f2bfs(v0.y); s[2] = f2bfs(v0.z); s[3] = f2bfs(v0.w);
                        s[4] = f2bfs(v1.x); s[5] = f2bfs(v1.y); s[6] = f2bfs(v1.z); s[7] = f2bfs(v1.w);
                        xsF[f] = s;
                    }
                }
            }
        }
    }
}

extern "C" void kernel_launch(void* const* d_in, const int* in_sizes, int n_in,
                              void* d_out, int out_size, void* d_ws, size_t ws_size,
                              hipStream_t stream) {
    const float* x = (const float*)d_in[0];
    const float* W = (const float*)d_in[1];
    const float* U = (const float*)d_in[2];
    const float* bias = (const float*)d_in[3];
    float* out = (float*)d_out;

    char* wsb = (char*)d_ws;
    // layout: bar(4K) | hbuf(256K) | U16T(8M) | W16T(8M) | x16(64M) | xW
    unsigned int* bar = (unsigned int*)wsb;
    unsigned short* hbuf = (unsigned short*)(wsb + 4096);
    unsigned short* u16t = (unsigned short*)(wsb + 266240);
    unsigned short* w16t = (unsigned short*)(wsb + 266240 + 8388608);
    unsigned short* x16 = (unsigned short*)(wsb + 17043456);
    void* xw = (void*)(wsb + 84152320);

    const size_t base_no_x16 = 17043456ull;
    const size_t base = 84152320ull;
    const size_t need1 = base + 268435456ull;   // xW bf16
    const size_t need2 = base + 536870912ull;   // xW fp32

    int xw_mode, use_x16;
    if (ws_size >= need2)      { xw_mode = 2; use_x16 = 1; }
    else if (ws_size >= need1) { xw_mode = 1; use_x16 = 1; }
    else if (ws_size >= base)  { xw_mode = 0; use_x16 = 1; }
    else                       { xw_mode = 0; use_x16 = 0; (void)base_no_x16; }

    const int n4 = (Bc * Sc * Dc) / 4;
    hipLaunchKernelGGL(prep_misc, dim3(2048), dim3(256), 0, stream, x, x16, bar, n4, use_x16);
    hipLaunchKernelGGL(transpose_bf16, dim3(1024), dim3(256), 0, stream, U, u16t);
    hipLaunchKernelGGL(transpose_bf16, dim3(1024), dim3(256), 0, stream, W, w16t);
    if (xw_mode >= 1)
        hipLaunchKernelGGL(gemm_xw, dim3(32768), dim3(256), 0, stream, x16, w16t, xw, xw_mode);
    hipLaunchKernelGGL(lstm_rec, dim3(256), dim3(256), 0, stream,
                       x16, x, w16t, u16t, bias, xw, hbuf, bar, out, xw_mode, use_x16);
}

// Round 2
// 4734.322 us; speedup vs baseline: 3.8522x; 1.3316x over previous
//
#include <hip/hip_runtime.h>
#include <hip/hip_bf16.h>
#include <cstddef>

// LSTM B=64,S=512,D=H=1024. Round 4 structure:
//  prep: zero tagged-h buffer + x->bf16 ; transpose W,U -> [4096][1024] bf16
//  gemm_xw: xW = x@W precomputed (fp32 if ws allows, else bf16, else in-loop).
//   R4: 128-row m-tile per WG (B-frags reused x2) + XCD-chunked swizzle so each
//   XCD's 8 nt-slices (1MB of B) stay L2-resident.
//  lstm_rec: 256 WGs x 256 thr. 4 batch-blocks of 16 batches, 64 WGs/block each
//   owning 16 h-cols. U-slice in registers.
//   R4: NO BARRIER. h exchanged as GEN-TAGGED DWORDS ((h16<<16)|gen) via sc1
//   stores; tag is co-atomic with data (single dword store), so no producer
//   vmcnt/flag/tree. Consumers poll their own h-tile with relaxed-agent loads
//   until all 64 tags == t+1 -- detection and h-load are the SAME round trip.
//   Critical path/step: ~2 L3 round trips (was ~6).
//   Overwrite-safety: WG writes gen t+3 into slot t&1 only after observing all
//   gens t+2 in slot (t+1)&1; each WG stores gen t+2 only after fully consuming
//   slot t&1 => no producer can clobber a slot still being polled. '==' check
//   turns any protocol violation into a hang, not silent corruption.

typedef __attribute__((ext_vector_type(8))) short short8;
typedef __attribute__((ext_vector_type(4))) float f32x4;

static constexpr int Bc = 64, Sc = 512, Dc = 1024, Hc = 1024, G4c = 4096;

__device__ __forceinline__ unsigned short f2bf(float f) {
    unsigned int u = __float_as_uint(f);
    u = u + 0x7FFFu + ((u >> 16) & 1u);   // RNE
    return (unsigned short)(u >> 16);
}
__device__ __forceinline__ short f2bfs(float f) { return (short)f2bf(f); }
__device__ __forceinline__ float bf2f(unsigned short u) { return __uint_as_float(((unsigned int)u) << 16); }
__device__ __forceinline__ float sigmoidf_(float x) { return 1.0f / (1.0f + __expf(-x)); }
__device__ __forceinline__ float tanhf_(float x) { return 1.0f - 2.0f / (__expf(2.0f * x) + 1.0f); }

// ---------------- prep: zero tagged-h buffer + x fp32 -> bf16 ----------------
__global__ void __launch_bounds__(256) prep_misc(const float* __restrict__ x,
                                                 unsigned short* __restrict__ x16,
                                                 unsigned int* __restrict__ hbufd,
                                                 int n4, int use_x16) {
    const int stride = gridDim.x * 256;
    const int j0 = blockIdx.x * 256 + threadIdx.x;
    for (int k = j0; k < 2 * Bc * Hc; k += stride) hbufd[k] = 0u;   // tags=0 (gen starts at 1)
    if (!use_x16) return;
    for (int i = j0; i < n4; i += stride) {
        const float4 v = ((const float4*)x)[i];
        ushort4 o;
        o.x = f2bf(v.x); o.y = f2bf(v.y); o.z = f2bf(v.z); o.w = f2bf(v.w);
        ((ushort4*)x16)[i] = o;
    }
}

// ---------------- transpose [1024][4096] fp32 -> [4096][1024] bf16 ----------------
__global__ void __launch_bounds__(256) transpose_bf16(const float* __restrict__ src,
                                                      unsigned short* __restrict__ dst) {
    __shared__ unsigned short T[64][72];
    const int kt = blockIdx.x >> 6;   // 0..15
    const int gt = blockIdx.x & 63;   // 0..63
    const int tr = threadIdx.x >> 6;  // 0..3
    const int tc = threadIdx.x & 63;  // 0..63
#pragma unroll
    for (int i = 0; i < 16; ++i) {
        const int r = i * 4 + tr;
        T[tc][r] = f2bf(src[(size_t)(kt * 64 + r) * G4c + gt * 64 + tc]);
    }
    __syncthreads();
#pragma unroll
    for (int i = 0; i < 16; ++i) {
        const int g = i * 4 + tr;
        dst[(size_t)(gt * 64 + g) * 1024 + kt * 64 + tc] = T[g][tc];
    }
}

// ---------------- xW GEMM: M=32768 (b,s), N=4096, K=1024; out layout [s][b][4096] ----------------
// 128-row m-tile per WG: two A frags share each B frag (frag-loads/tile 1.25->0.75).
// XCD-chunked swizzle: XCD k handles nt in [8k,8k+8) => 1MB B slice L2-resident.
__global__ void __launch_bounds__(256) gemm_xw(const unsigned short* __restrict__ x16,
                                               const unsigned short* __restrict__ w16t,
                                               void* __restrict__ xw, int mode) {
    const int wg = blockIdx.x;                  // 16384 WGs
    const int swz = (wg & 7) * 2048 + (wg >> 3);
    const int nt = swz >> 8;                    // 0..63
    const int mt = swz & 255;                   // 0..255 (128 rows each)
    const int w = threadIdx.x >> 6;
    const int lane = threadIdx.x & 63;
    const int q = lane >> 4, l16 = lane & 15;

    const unsigned short* abase = x16 + (size_t)(mt * 128 + w * 16 + l16) * 1024 + q * 8;
    const unsigned short* bbase = w16t + (size_t)(nt * 64 + l16) * 1024 + q * 8;

    f32x4 acc0[4] = {{0,0,0,0},{0,0,0,0},{0,0,0,0},{0,0,0,0}};
    f32x4 acc1[4] = {{0,0,0,0},{0,0,0,0},{0,0,0,0},{0,0,0,0}};
#pragma unroll 4
    for (int kk = 0; kk < 32; ++kk) {
        short8 a0 = *(const short8*)(abase + kk * 32);
        short8 a1 = *(const short8*)(abase + 64 * 1024 + kk * 32);
#pragma unroll
        for (int j = 0; j < 4; ++j) {
            short8 b = *(const short8*)(bbase + (size_t)j * 16 * 1024 + kk * 32);
            acc0[j] = __builtin_amdgcn_mfma_f32_16x16x32_bf16(a0, b, acc0[j], 0, 0, 0);
            acc1[j] = __builtin_amdgcn_mfma_f32_16x16x32_bf16(a1, b, acc1[j], 0, 0, 0);
        }
    }
    const int m0 = mt * 128 + w * 16 + q * 4;
#pragma unroll
    for (int half = 0; half < 2; ++half) {
#pragma unroll
        for (int j = 0; j < 4; ++j)
#pragma unroll
            for (int r = 0; r < 4; ++r) {
                const int m = m0 + half * 64 + r;
                const int b = m >> 9, s = m & 511;
                const size_t o = ((size_t)s * 64 + b) * G4c + nt * 64 + j * 16 + l16;
                const float v = half ? acc1[j][r] : acc0[j][r];
                if (mode == 2) ((float*)xw)[o] = v;
                else ((unsigned short*)xw)[o] = f2bf(v);
            }
    }
}

// ---------------- recurrence (barrier-free, gen-tagged h exchange) ----------------
__global__ void __launch_bounds__(256, 1) lstm_rec(
    const unsigned short* __restrict__ x16, const float* __restrict__ x,
    const unsigned short* __restrict__ w16t, const unsigned short* __restrict__ u16t,
    const float* __restrict__ bias, const void* __restrict__ xw,
    unsigned int* __restrict__ hbufd,
    float* __restrict__ out, int xw_mode, int use_x16) {
    __shared__ short8 hsF[2048];   // 32 KB: A-frags of h, [kk][lane]
    __shared__ short8 xsF[2048];   // 32 KB: A-frags of x_t (mode 0 only)
    __shared__ float gbuf[4][16][17];

    const int tid = threadIdx.x;
    const int blk = blockIdx.x >> 6;      // batch block 0..3
    const int cs = blockIdx.x & 63;       // col slice 0..63
    const int col0 = cs * 16;
    const int wv = tid >> 6;
    const int lane = tid & 63;
    const int q = lane >> 4, l16 = lane & 15;
    const int bb = tid >> 4, cc = tid & 15;   // elementwise (batch, col)
    const int gcol = col0 + cc;

    // bias registers
    const float bi = bias[gcol], bfv = bias[1024 + gcol], bg = bias[2048 + gcol], bo = bias[3072 + gcol];

    // U slice -> registers: 32 x short8 = 128 VGPRs
    short8 uf[32];
    {
        const unsigned short* ub = u16t + ((size_t)wv * 1024 + col0 + l16) * 1024 + q * 8;
#pragma unroll
        for (int kk = 0; kk < 32; ++kk) uf[kk] = *(const short8*)(ub + kk * 32);
    }
    // zero h frags (h_{-1} = 0)
    {
        const short8 z = {0, 0, 0, 0, 0, 0, 0, 0};
#pragma unroll
        for (int i = 0; i < 8; ++i) hsF[i * 256 + tid] = z;
    }
    // mode 0: stage x frags for t=0
    if (xw_mode == 0) {
#pragma unroll
        for (int i = 0; i < 8; ++i) {
            const int f = i * 256 + tid;
            const int kk = f >> 6, qq = (f >> 4) & 3, b2 = f & 15;
            if (use_x16) {
                const unsigned short* xs = x16 + ((size_t)(blk * 16 + b2) * Sc + 0) * Dc + kk * 32 + qq * 8;
                xsF[f] = *(const short8*)xs;
            } else {
                const float* xs = x + ((size_t)(blk * 16 + b2) * Sc + 0) * Dc + kk * 32 + qq * 8;
                float4 v0 = *(const float4*)xs, v1 = *(const float4*)(xs + 4);
                short8 s;
                s[0] = f2bfs(v0.x); s[1] = f2bfs(v0.y); s[2] = f2bfs(v0.z); s[3] = f2bfs(v0.w);
                s[4] = f2bfs(v1.x); s[5] = f2bfs(v1.y); s[6] = f2bfs(v1.z); s[7] = f2bfs(v1.w);
                xsF[f] = s;
            }
        }
    }
    // prefetch xW(t=0)
    float pxi = 0.f, pxf = 0.f, pxg = 0.f, pxo = 0.f;
    if (xw_mode == 1) {
        const unsigned short* p = (const unsigned short*)xw + ((size_t)0 * 64 + blk * 16 + bb) * G4c + gcol;
        pxi = bf2f(p[0]); pxf = bf2f(p[1024]); pxg = bf2f(p[2048]); pxo = bf2f(p[3072]);
    } else if (xw_mode == 2) {
        const float* p = (const float*)xw + ((size_t)0 * 64 + blk * 16 + bb) * G4c + gcol;
        pxi = p[0]; pxf = p[1024]; pxg = p[2048]; pxo = p[3072];
    }

    // per-thread base for the h-stage reads (frag f = i*256+tid)
    const int kk0 = tid >> 6, qq0 = (tid >> 4) & 3, b20 = tid & 15;

    float c = 0.f;
    for (int t = 0; t < Sc; ++t) {
        __syncthreads();   // staging (or init) visible
        f32x4 a0 = {0, 0, 0, 0}, a1 = {0, 0, 0, 0}, a2 = {0, 0, 0, 0}, a3 = {0, 0, 0, 0};
#pragma unroll
        for (int kk = 0; kk < 32; kk += 4) {
            a0 = __builtin_amdgcn_mfma_f32_16x16x32_bf16(hsF[kk * 64 + lane], uf[kk], a0, 0, 0, 0);
            a1 = __builtin_amdgcn_mfma_f32_16x16x32_bf16(hsF[(kk + 1) * 64 + lane], uf[kk + 1], a1, 0, 0, 0);
            a2 = __builtin_amdgcn_mfma_f32_16x16x32_bf16(hsF[(kk + 2) * 64 + lane], uf[kk + 2], a2, 0, 0, 0);
            a3 = __builtin_amdgcn_mfma_f32_16x16x32_bf16(hsF[(kk + 3) * 64 + lane], uf[kk + 3], a3, 0, 0, 0);
        }
        if (xw_mode == 0) {
            const unsigned short* wb = w16t + ((size_t)wv * 1024 + col0 + l16) * 1024 + q * 8;
#pragma unroll
            for (int kk = 0; kk < 32; kk += 4) {
                short8 w0 = *(const short8*)(wb + kk * 32);
                a0 = __builtin_amdgcn_mfma_f32_16x16x32_bf16(xsF[kk * 64 + lane], w0, a0, 0, 0, 0);
                short8 w1 = *(const short8*)(wb + (kk + 1) * 32);
                a1 = __builtin_amdgcn_mfma_f32_16x16x32_bf16(xsF[(kk + 1) * 64 + lane], w1, a1, 0, 0, 0);
                short8 w2 = *(const short8*)(wb + (kk + 2) * 32);
                a2 = __builtin_amdgcn_mfma_f32_16x16x32_bf16(xsF[(kk + 2) * 64 + lane], w2, a2, 0, 0, 0);
                short8 w3 = *(const short8*)(wb + (kk + 3) * 32);
                a3 = __builtin_amdgcn_mfma_f32_16x16x32_bf16(xsF[(kk + 3) * 64 + lane], w3, a3, 0, 0, 0);
            }
        }
#pragma unroll
        for (int r = 0; r < 4; ++r) gbuf[wv][q * 4 + r][l16] = (a0[r] + a1[r]) + (a2[r] + a3[r]);
        __syncthreads();
        // elementwise: thread (bb, cc)
        float gi = gbuf[0][bb][cc] + pxi + bi;
        float gf = gbuf[1][bb][cc] + pxf + bfv;
        float gg = gbuf[2][bb][cc] + pxg + bg;
        float go = gbuf[3][bb][cc] + pxo + bo;
        gi = sigmoidf_(gi); gf = sigmoidf_(gf); gg = tanhf_(gg); go = sigmoidf_(go);
        c = gf * c + gi * gg;
        const float h = go * tanhf_(c);
        // gen-tagged h store: single dword (tag co-atomic with data), sc1
        {
            const unsigned int tagv = ((unsigned int)f2bf(h) << 16) | (unsigned int)(t + 1);
            unsigned int* hp = hbufd + (((size_t)(t & 1)) << 16) + (size_t)(blk * 16 + bb) * 1024 + gcol;
            asm volatile("global_store_dword %0, %1, off sc1" :: "v"(hp), "v"(tagv) : "memory");
        }
        out[((size_t)(blk * 16 + bb) * Sc + t) * Hc + gcol] = h;
        if (t == Sc - 1) {
            out[(size_t)Bc * Sc * Hc + (size_t)(blk * 16 + bb) * Hc + gcol] = h;
            out[(size_t)Bc * Sc * Hc + (size_t)Bc * Hc + (size_t)(blk * 16 + bb) * Hc + gcol] = c;
        }
        if (t < Sc - 1) {
            // xW(t+1) prefetch: cached loads, consumed next elementwise (ample slack)
            if (xw_mode == 1) {
                const unsigned short* p = (const unsigned short*)xw + ((size_t)(t + 1) * 64 + blk * 16 + bb) * G4c + gcol;
                pxi = bf2f(p[0]); pxf = bf2f(p[1024]); pxg = bf2f(p[2048]); pxo = bf2f(p[3072]);
            } else if (xw_mode == 2) {
                const float* p = (const float*)xw + ((size_t)(t + 1) * 64 + blk * 16 + bb) * G4c + gcol;
                pxi = p[0]; pxf = p[1024]; pxg = p[2048]; pxo = p[3072];
            }
            // poll own h tile until all 64 tags == t+1; data arrives with the poll
            const unsigned int gen = (unsigned int)(t + 1);
            const unsigned long long genpat = (unsigned long long)gen | ((unsigned long long)gen << 32);
            const unsigned long long* pd = (const unsigned long long*)hbufd +
                (((((size_t)(t & 1)) << 16) + (size_t)(blk * 16 + b20) * 1024 + kk0 * 32 + qq0 * 8) >> 1);
            unsigned long long hv[32];
            for (;;) {
#pragma unroll
                for (int i = 0; i < 8; ++i)
#pragma unroll
                    for (int j = 0; j < 4; ++j)
                        hv[i * 4 + j] = __hip_atomic_load(pd + i * 64 + j, __ATOMIC_RELAXED, __HIP_MEMORY_SCOPE_AGENT);
                unsigned long long bad = 0ull;
#pragma unroll
                for (int i = 0; i < 32; ++i) bad |= (hv[i] ^ genpat) & 0x0000FFFF0000FFFFull;
                if (bad == 0ull) break;
                __builtin_amdgcn_s_sleep(1);
            }
            // extract h16 (high halves) -> bf16 frags -> LDS
#pragma unroll
            for (int i = 0; i < 8; ++i) {
                short8 s;
                unsigned int* sp = (unsigned int*)&s;
#pragma unroll
                for (int j = 0; j < 4; ++j) {
                    const unsigned long long v = hv[i * 4 + j];
                    sp[j] = ((unsigned int)(v >> 16) & 0xFFFFu) | ((unsigned int)(v >> 32) & 0xFFFF0000u);
                }
                hsF[i * 256 + tid] = s;
            }
            // stage x_{t+1} frags (mode 0) -- read-only input, ordinary cached loads
            if (xw_mode == 0) {
#pragma unroll
                for (int i = 0; i < 8; ++i) {
                    const int f = i * 256 + tid;
                    const int kk = f >> 6, qq = (f >> 4) & 3, b2 = f & 15;
                    if (use_x16) {
                        const unsigned short* xs = x16 + ((size_t)(blk * 16 + b2) * Sc + (t + 1)) * Dc + kk * 32 + qq * 8;
                        xsF[f] = *(const short8*)xs;
                    } else {
                        const float* xs = x + ((size_t)(blk * 16 + b2) * Sc + (t + 1)) * Dc + kk * 32 + qq * 8;
                        float4 v0 = *(const float4*)xs, v1 = *(const float4*)(xs + 4);
                        short8 s;
                        s[0] = f2bfs(v0.x); s[1] = f2bfs(v0.y); s[2] = f2bfs(v0.z); s[3] = f2bfs(v0.w);
                        s[4] = f2bfs(v1.x); s[5] = f2bfs(v1.y); s[6] = f2bfs(v1.z); s[7] = f2bfs(v1.w);
                        xsF[f] = s;
                    }
                }
            }
        }
    }
}

extern "C" void kernel_launch(void* const* d_in, const int* in_sizes, int n_in,
                              void* d_out, int out_size, void* d_ws, size_t ws_size,
                              hipStream_t stream) {
    const float* x = (const float*)d_in[0];
    const float* W = (const float*)d_in[1];
    const float* U = (const float*)d_in[2];
    const float* bias = (const float*)d_in[3];
    float* out = (float*)d_out;

    char* wsb = (char*)d_ws;
    // layout: hbufd(512K) | U16T(8M) | W16T(8M) | x16(64M) | xW
    unsigned int* hbufd = (unsigned int*)wsb;
    unsigned short* u16t = (unsigned short*)(wsb + 524288);
    unsigned short* w16t = (unsigned short*)(wsb + 524288 + 8388608);
    unsigned short* x16 = (unsigned short*)(wsb + 17301504);
    void* xw = (void*)(wsb + 84410368);

    const size_t base = 84410368ull;
    const size_t need1 = base + 268435456ull;   // xW bf16
    const size_t need2 = base + 536870912ull;   // xW fp32

    int xw_mode, use_x16;
    if (ws_size >= need2)      { xw_mode = 2; use_x16 = 1; }
    else if (ws_size >= need1) { xw_mode = 1; use_x16 = 1; }
    else if (ws_size >= base)  { xw_mode = 0; use_x16 = 1; }
    else                       { xw_mode = 0; use_x16 = 0; }

    const int n4 = (Bc * Sc * Dc) / 4;
    hipLaunchKernelGGL(prep_misc, dim3(2048), dim3(256), 0, stream, x, x16, hbufd, n4, use_x16);
    hipLaunchKernelGGL(transpose_bf16, dim3(1024), dim3(256), 0, stream, U, u16t);
    hipLaunchKernelGGL(transpose_bf16, dim3(1024), dim3(256), 0, stream, W, w16t);
    if (xw_mode >= 1)
        hipLaunchKernelGGL(gemm_xw, dim3(16384), dim3(256), 0, stream, x16, w16t, xw, xw_mode);
    hipLaunchKernelGGL(lstm_rec, dim3(256), dim3(256), 0, stream,
                       x16, x, w16t, u16t, bias, xw, hbufd, out, xw_mode, use_x16);
}